// Round 6
// baseline (367.517 us; speedup 1.0000x reference)
//
#include <hip/hip_runtime.h>
#include <math.h>

#define NB 20
#define SDIM 160   // 20*8
#define H1 64
#define TWO_PI_F 6.28318530717958647692f

// ws layout (floats), all rows float4-aligned
#define WS_DROW  0      // 64 density rows x 28: [w0..w23, beff, w2q, pad, pad]
#define WS_CROW  1792   // 64 color rows  x 32: [w0..w23, beff, wd, w2c0, w2c1, w2c2, pad x3]
#define WS_MISC  3840   // [0]=fq_b2, [1..3]=col_b2

typedef float f2 __attribute__((ext_vector_type(2)));

__device__ __forceinline__ float fast_sigmoid(float x){ return 1.0f/(1.0f+__expf(-x)); }
__device__ __forceinline__ float fast_softplus(float x){
    return fmaxf(x, 0.0f) + __logf(1.0f + __expf(-fabsf(x)));
}
__device__ __forceinline__ float fast_rcp(float x){ return __builtin_amdgcn_rcpf(x); }
__device__ __forceinline__ float fast_rsq(float x){ return __builtin_amdgcn_rsqf(x); }
__device__ __forceinline__ float bperm(float v, int srcLane){
    return __int_as_float(__builtin_amdgcn_ds_bpermute(srcLane << 2, __float_as_int(v)));
}
__device__ __forceinline__ float rdlane(float v, int l){
    return __int_as_float(__builtin_amdgcn_readlane(__float_as_int(v), l));
}
__device__ __forceinline__ float getS(float s0, float s1, float s2, int f){
    return (f < 64) ? rdlane(s0, f) : (f < 128) ? rdlane(s1, f - 64) : rdlane(s2, f - 128);
}
__device__ __forceinline__ f2 pkfma(f2 a, f2 b, f2 c){
    return __builtin_elementwise_fma(a, b, c);   // -> v_pk_fma_f32 on gfx950
}

// ---------------------------------------------------------------------------
// 4-wave blob simulation (unchanged from round 5).
// ---------------------------------------------------------------------------
__global__ __launch_bounds__(256, 1) void blob_sim_kernel(
    const float* __restrict__ initial_state,
    const float* __restrict__ dyn_w1, const float* __restrict__ dyn_b1,
    const float* __restrict__ dyn_w2, const float* __restrict__ dyn_b2,
    const float* __restrict__ couplingP, const float* __restrict__ dampingP,
    const float* __restrict__ interaction,
    const float* __restrict__ summ_w, const float* __restrict__ summ_b,
    const float* __restrict__ fq_w1, const float* __restrict__ fq_b1,
    const float* __restrict__ fq_w2, const float* __restrict__ fq_b2,
    const float* __restrict__ col_w1, const float* __restrict__ col_b1,
    const float* __restrict__ col_w2, const float* __restrict__ col_b2,
    const int* __restrict__ tP,
    float* __restrict__ ws)
{
    __shared__ float sW1T[160*64];   // staging [k][j]
    __shared__ float sW2T[64*128];   // staging [k][o], o<100 used, pad 0
    __shared__ float sP1L[64*4];     // phase-1 partials [j][wave]
    __shared__ float sDnP[128*4];    // phase-2 partials [o][wave]
    __shared__ float sFr[64];        // forces [b*3+c]
    __shared__ float sPosL[64];      // positions [b*3+c], maintained by wave 3
    __shared__ float sSum[32];

    const int tid  = threadIdx.x;
    const int wv   = tid >> 6;
    const int lane = tid & 63;

    // ---- one-time staging ----
    for (int idx = tid; idx < 160*64; idx += 256){
        int j = idx / 160, k = idx - j*160;
        sW1T[k*64 + j] = dyn_w1[idx];
    }
    for (int idx = tid; idx < 64*100; idx += 256){
        int k = idx / 100, o = idx - k*100;
        int ob = o / 5, oc = o - ob*5;
        sW2T[k*128 + o] = dyn_w2[(ob*8 + 3 + oc)*H1 + k];
    }
    for (int idx = tid; idx < 64*28; idx += 256){   // zero-pad o in [100,128)
        int k = idx / 28, o = 100 + (idx - (idx/28)*28);
        sW2T[k*128 + o] = 0.0f;
    }
    if (tid < 60) sPosL[tid] = initial_state[(tid/3)*8 + (tid - (tid/3)*3)];
    if (tid < 64) sP1L[tid*4 + 3] = 0.0f;   // wave-3 never writes phase-1 partials
    __syncthreads();

    // ---- per-wave register weights ----
    float w1s[54];
    if (wv < 3){
        const int kb = wv*53;
        #pragma unroll
        for (int t2 = 0; t2 < 54; ++t2) w1s[t2] = sW1T[(kb + t2)*64 + lane];
    }
    float w2a16[16], w2b16[16];
    {
        const int kb2 = wv*16;
        #pragma unroll
        for (int t2 = 0; t2 < 16; ++t2){
            w2a16[t2] = sW2T[(kb2 + t2)*128 + lane];
            w2b16[t2] = sW2T[(kb2 + t2)*128 + 64 + lane];
        }
    }

    // wave-3 force decomposition: lane = jg*20 + fi, jj range [jg*7, jg*7+7)
    const int fi  = lane % 20;
    const int jg  = lane / 20;
    const int jj0 = jg * 7;
    float rintw[7];
    #pragma unroll
    for (int u = 0; u < 7; ++u){
        int jj = jj0 + u;
        rintw[u] = (wv == 3 && lane < 60 && jj < NB) ? interaction[fi*NB + jj] : 0.0f;
    }

    // ---- replicated state ----
    float s0 = initial_state[lane];
    float s1 = initial_state[64 + lane];
    float s2 = (lane < 32) ? initial_state[128 + lane] : 0.0f;

    const float b1r = dyn_b1[lane];
    float b2ar, b2br;
    { int b = lane/5, c = lane - (lane/5)*5; b2ar = dyn_b2[b*8 + 3 + c]; }
    { int o2 = 64 + lane;
      if (o2 < 100){ int b = o2/5, c = o2 - (o2/5)*5; b2br = dyn_b2[b*8 + 3 + c]; }
      else b2br = 0.0f; }
    const float bA0 = (wv == 0) ? b2ar : 0.0f;
    const float bB0 = (wv == 0) ? b2br : 0.0f;

    const float coupling = couplingP[0];
    const float damping  = dampingP[0];
    const int tv = tP[0];
    int n_steps = (int)((double)tv / 0.01);   // replicates Python int(t/DT): 2 -> 199
    if (n_steps < 1) n_steps = 1;
    const float adt = (float)((double)tv / (double)n_steps);

    const int cc  = lane & 7;
    const int bb  = lane >> 3;
    const int cm3 = (cc >= 3) ? cc - 3 : 0;
    const int lp3 = (lane + 3 > 63) ? 63 : lane + 3;

    for (int step = 0; step < n_steps; ++step){
        float fx = 0.f, fy = 0.f, fz = 0.f;
        if (wv < 3){
            float aa[4] = {0.f, 0.f, 0.f, 0.f};
            if (wv == 0){
                #pragma unroll
                for (int t2 = 0; t2 < 53; ++t2)
                    aa[t2&3] = fmaf(rdlane(s0, t2), w1s[t2], aa[t2&3]);
            } else if (wv == 1){
                #pragma unroll
                for (int t2 = 0; t2 < 53; ++t2){
                    int k = 53 + t2;
                    float sv = (k < 64) ? rdlane(s0, k) : rdlane(s1, k - 64);
                    aa[t2&3] = fmaf(sv, w1s[t2], aa[t2&3]);
                }
            } else {
                #pragma unroll
                for (int t2 = 0; t2 < 54; ++t2){
                    int k = 106 + t2;
                    float sv = (k < 128) ? rdlane(s1, k - 64) : rdlane(s2, k - 128);
                    aa[t2&3] = fmaf(sv, w1s[t2], aa[t2&3]);
                }
            }
            sP1L[lane*4 + wv] = (aa[0] + aa[1]) + (aa[2] + aa[3]);
        } else {
            float px = sPosL[fi*3+0], py = sPosL[fi*3+1], pz = sPosL[fi*3+2];
            #pragma unroll
            for (int u = 0; u < 7; ++u){
                int jj = jj0 + u;
                int js = (jj < NB) ? jj : 0;
                float dx = px - sPosL[js*3+0];
                float dy = py - sPosL[js*3+1];
                float dz = pz - sPosL[js*3+2];
                float e  = fmaf(dx,dx, fmaf(dy,dy, fmaf(dz,dz, 1e-6f)));
                float d  = e * fast_rsq(e);
                float mag = rintw[u] * fast_rcp(e + 1.0f);
                float w   = mag * fast_rcp(d + 1e-6f);
                fx = fmaf(dx, w, fx);
                fy = fmaf(dy, w, fy);
                fz = fmaf(dz, w, fz);
            }
            fx += bperm(fx, lane+20) + bperm(fx, lane+40);
            fy += bperm(fy, lane+20) + bperm(fy, lane+40);
            fz += bperm(fz, lane+20) + bperm(fz, lane+40);
        }

        __syncthreads();   // B1: phase-1 partials visible

        if (wv == 3 && lane < NB){
            sFr[lane*3+0] = fx; sFr[lane*3+1] = fy; sFr[lane*3+2] = fz;
        }

        float4 pp = *(const float4*)&sP1L[lane*4];
        float hv = (pp.x + pp.y) + pp.z + b1r;
        hv = fminf(fmaxf(hv, -15.0f), 15.0f);
        float e2v = __expf(2.0f * hv);
        float hreg = (e2v - 1.0f) * fast_rcp(e2v + 1.0f);

        {
            float dA0=0.f, dA1=0.f, dB0=0.f, dB1=0.f;
            const int kb2 = wv*16;
            #pragma unroll
            for (int t2 = 0; t2 < 16; t2 += 2){
                float h0 = rdlane(hreg, kb2 + t2);
                float h1 = rdlane(hreg, kb2 + t2 + 1);
                dA0 = fmaf(h0, w2a16[t2],   dA0);
                dA1 = fmaf(h1, w2a16[t2+1], dA1);
                dB0 = fmaf(h0, w2b16[t2],   dB0);
                dB1 = fmaf(h1, w2b16[t2+1], dB1);
            }
            sDnP[lane*4 + wv]      = dA0 + dA1 + bA0;
            sDnP[(64+lane)*4 + wv] = dB0 + dB1 + bB0;
        }

        __syncthreads();   // B2: dn partials + forces visible

        {
            float v0 = bperm(s0, lp3);
            float v1 = bperm(s1, lp3);
            float v2 = bperm(s2, lp3);
            int o0 = bb*5 + cm3;
            int o1 = 40 + o0;
            int o2 = 80 + o0;
            float4 q0 = *(const float4*)&sDnP[o0*4];
            float4 q1 = *(const float4*)&sDnP[o1*4];
            float4 q2 = *(const float4*)&sDnP[o2*4];
            float dn0 = (q0.x + q0.y) + (q0.z + q0.w);
            float dn1 = (q1.x + q1.y) + (q1.z + q1.w);
            float dn2 = (q2.x + q2.y) + (q2.z + q2.w);
            float F0 = sFr[bb*3 + cm3];
            float F1 = sFr[(8+bb)*3 + cm3];
            float F2 = sFr[(lane < 32) ? (16+bb)*3 + cm3 : 0];

            float dv0 = (cc < 3) ? v0
                      : (cc < 6) ? fmaf(-damping, s0, fmaf(coupling, F0, dn0))
                      : (cc == 6) ? fmaf(-0.05f, s0 - 1.0f, dn0)
                                  : fmaf(-0.05f, s0 - 0.5f, dn0);
            float dv1 = (cc < 3) ? v1
                      : (cc < 6) ? fmaf(-damping, s1, fmaf(coupling, F1, dn1))
                      : (cc == 6) ? fmaf(-0.05f, s1 - 1.0f, dn1)
                                  : fmaf(-0.05f, s1 - 0.5f, dn1);
            float dv2 = (cc < 3) ? v2
                      : (cc < 6) ? fmaf(-damping, s2, fmaf(coupling, F2, dn2))
                      : (cc == 6) ? fmaf(-0.05f, s2 - 1.0f, dn2)
                                  : fmaf(-0.05f, s2 - 0.5f, dn2);

            s0 = fmaf(adt, dv0, s0);
            s1 = fmaf(adt, dv1, s1);
            s2 = fmaf(adt, dv2, s2);

            if (wv == 3 && cc < 3){
                sPosL[bb*3 + cc]      = s0;
                sPosL[(8+bb)*3 + cc]  = s1;
                if (lane < 32) sPosL[(16+bb)*3 + cc] = s2;
            }
        }
    }

    if (wv != 0) return;   // tail on wave 0 only (no barriers below)

    // ---- summary = summ_w @ flat + summ_b ----
    {
        int sbase = (lane & 31) * SDIM;
        float sa = summ_b[lane & 31];
        #pragma unroll
        for (int k = 0; k < SDIM; ++k)
            sa = fmaf(getS(s0,s1,s2,k), summ_w[sbase + k], sa);
        if (lane < 32) sSum[lane] = sa;
    }

    // ---- pack padded field-weight rows; fold summary into effective biases ----
    {
        const int j = lane;
        int base = WS_DROW + j*28;
        #pragma unroll
        for (int k = 0; k < 24; ++k) ws[base + k] = fq_w1[j*56 + k];
        float bq = fq_b1[j];
        #pragma unroll
        for (int m = 0; m < 32; ++m) bq = fmaf(sSum[m], fq_w1[j*56 + 24 + m], bq);
        ws[base + 24] = bq;
        ws[base + 25] = fq_w2[j];
        ws[base + 26] = 0.0f;
        ws[base + 27] = 0.0f;
        base = WS_CROW + j*32;
        #pragma unroll
        for (int k = 0; k < 24; ++k) ws[base + k] = col_w1[j*57 + k];
        float bc = col_b1[j];
        #pragma unroll
        for (int m = 0; m < 32; ++m) bc = fmaf(sSum[m], col_w1[j*57 + 24 + m], bc);
        ws[base + 24] = bc;
        ws[base + 25] = col_w1[j*57 + 56];
        ws[base + 26] = col_w2[j];
        ws[base + 27] = col_w2[64 + j];
        ws[base + 28] = col_w2[128 + j];
        ws[base + 29] = 0.0f;
        ws[base + 30] = 0.0f;
        ws[base + 31] = 0.0f;
    }
    if (lane == 0){
        ws[WS_MISC + 0] = fq_b2[0];
        ws[WS_MISC + 1] = col_b2[0];
        ws[WS_MISC + 2] = col_b2[1];
        ws[WS_MISC + 3] = col_b2[2];
    }
}

// ---------------------------------------------------------------------------
// Field eval: 2 points per thread, v_pk_fma_f32 packed dots. Weights flow
// uniform ws -> s_load -> SGPR pairs (VOP3P allows one scalar source).
// ---------------------------------------------------------------------------
__global__ __launch_bounds__(256) void field_kernel(
    const float* __restrict__ p,
    const float* __restrict__ ws,
    float* __restrict__ out, int N)
{
    const int tid = threadIdx.x;
    const int iA  = blockIdx.x * 512 + tid;
    const int iB  = iA + 256;
    const int lA  = (iA < N) ? iA : 0;
    const int lB  = (iB < N) ? iB : 0;

    // penc as 12 f2 pairs per point: pair q = (e[2q], e[2q+1])
    f2 eA[12], eB[12];
    {
        const float a0 = p[3*lA], a1 = p[3*lA+1], a2 = p[3*lA+2];
        const float b0 = p[3*lB], b1 = p[3*lB+1], b2 = p[3*lB+2];
        float tA[24], tB[24];
        #pragma unroll
        for (int f = 0; f < 4; ++f){
            const float w = TWO_PI_F * (float)(1 << f);
            float s, c;
            __sincosf(w * a0, &s, &c); tA[f*6+0] = s; tA[f*6+3] = c;
            __sincosf(w * a1, &s, &c); tA[f*6+1] = s; tA[f*6+4] = c;
            __sincosf(w * a2, &s, &c); tA[f*6+2] = s; tA[f*6+5] = c;
            __sincosf(w * b0, &s, &c); tB[f*6+0] = s; tB[f*6+3] = c;
            __sincosf(w * b1, &s, &c); tB[f*6+1] = s; tB[f*6+4] = c;
            __sincosf(w * b2, &s, &c); tB[f*6+2] = s; tB[f*6+5] = c;
        }
        #pragma unroll
        for (int q = 0; q < 12; ++q){
            eA[q] = (f2){tA[2*q], tA[2*q+1]};
            eB[q] = (f2){tB[2*q], tB[2*q+1]};
        }
    }

    const float m0  = ws[WS_MISC + 0];
    const float mc0 = ws[WS_MISC + 1];
    const float mc1 = ws[WS_MISC + 2];
    const float mc2 = ws[WS_MISC + 3];

    // ---- density MLP: row = 14 f2 {w x12, {beff,w2q}, pad} ----
    float dA = m0, dB = m0;
    {
        const f2* R = (const f2*)(ws + WS_DROW);
        #pragma unroll 4
        for (int jj = 0; jj < 64; ++jj){
            const f2* r = R + jj*14;
            f2 aA0 = {0.f,0.f}, aA1 = {0.f,0.f};
            f2 aB0 = {0.f,0.f}, aB1 = {0.f,0.f};
            #pragma unroll
            for (int q = 0; q < 12; q += 2){
                f2 w0 = r[q], w1 = r[q+1];
                aA0 = pkfma(eA[q],   w0, aA0);
                aA1 = pkfma(eA[q+1], w1, aA1);
                aB0 = pkfma(eB[q],   w0, aB0);
                aB1 = pkfma(eB[q+1], w1, aB1);
            }
            f2 m = r[12];                    // {beff, w2q}
            f2 sA2 = aA0 + aA1, sB2 = aB0 + aB1;
            float aA = fmaxf(sA2.x + sA2.y + m.x, 0.0f);
            float aB = fmaxf(sB2.x + sB2.y + m.x, 0.0f);
            dA = fmaf(aA, m.y, dA);
            dB = fmaf(aB, m.y, dB);
        }
    }
    const float densA = fast_softplus(dA);
    const float densB = fast_softplus(dB);

    // ---- color MLP: row = 16 f2 {w x12, {beff,wd}, {w2c0,w2c1}, {w2c2,pad}, pad} ----
    float cA0 = mc0, cA1 = mc1, cA2 = mc2;
    float cB0 = mc0, cB1 = mc1, cB2 = mc2;
    {
        const f2* R = (const f2*)(ws + WS_CROW);
        #pragma unroll 4
        for (int jj = 0; jj < 64; ++jj){
            const f2* r = R + jj*16;
            f2 aA0 = {0.f,0.f}, aA1 = {0.f,0.f};
            f2 aB0 = {0.f,0.f}, aB1 = {0.f,0.f};
            #pragma unroll
            for (int q = 0; q < 12; q += 2){
                f2 w0 = r[q], w1 = r[q+1];
                aA0 = pkfma(eA[q],   w0, aA0);
                aA1 = pkfma(eA[q+1], w1, aA1);
                aB0 = pkfma(eB[q],   w0, aB0);
                aB1 = pkfma(eB[q+1], w1, aB1);
            }
            f2 m  = r[12];                   // {beff, wd}
            f2 c01 = r[13];                  // {w2c0, w2c1}
            f2 c2p = r[14];                  // {w2c2, pad}
            f2 sA2 = aA0 + aA1, sB2 = aB0 + aB1;
            float aA = sA2.x + sA2.y + m.x;
            float aB = sB2.x + sB2.y + m.x;
            aA = fmaxf(fmaf(densA, m.y, aA), 0.0f);
            aB = fmaxf(fmaf(densB, m.y, aB), 0.0f);
            cA0 = fmaf(aA, c01.x, cA0); cA1 = fmaf(aA, c01.y, cA1); cA2 = fmaf(aA, c2p.x, cA2);
            cB0 = fmaf(aB, c01.x, cB0); cB1 = fmaf(aB, c01.y, cB1); cB2 = fmaf(aB, c2p.x, cB2);
        }
    }

    float* oc = out + N;
    if (iA < N){
        out[iA] = densA;
        oc[3*iA + 0] = fast_sigmoid(cA0);
        oc[3*iA + 1] = fast_sigmoid(cA1);
        oc[3*iA + 2] = fast_sigmoid(cA2);
    }
    if (iB < N){
        out[iB] = densB;
        oc[3*iB + 0] = fast_sigmoid(cB0);
        oc[3*iB + 1] = fast_sigmoid(cB1);
        oc[3*iB + 2] = fast_sigmoid(cB2);
    }
}

extern "C" void kernel_launch(void* const* d_in, const int* in_sizes, int n_in,
                              void* d_out, int out_size, void* d_ws, size_t ws_size,
                              hipStream_t stream)
{
    const float* p             = (const float*)d_in[0];
    const float* initial_state = (const float*)d_in[1];
    const float* dyn_w1        = (const float*)d_in[2];
    const float* dyn_b1        = (const float*)d_in[3];
    const float* dyn_w2        = (const float*)d_in[4];
    const float* dyn_b2        = (const float*)d_in[5];
    const float* coupling      = (const float*)d_in[6];
    const float* damping       = (const float*)d_in[7];
    const float* interaction   = (const float*)d_in[8];
    const float* summ_w        = (const float*)d_in[9];
    const float* summ_b        = (const float*)d_in[10];
    const float* fq_w1         = (const float*)d_in[11];
    const float* fq_b1         = (const float*)d_in[12];
    const float* fq_w2         = (const float*)d_in[13];
    const float* fq_b2         = (const float*)d_in[14];
    const float* col_w1        = (const float*)d_in[15];
    const float* col_b1        = (const float*)d_in[16];
    const float* col_w2        = (const float*)d_in[17];
    const float* col_b2        = (const float*)d_in[18];
    const int*   tP            = (const int*)d_in[19];

    float* ws  = (float*)d_ws;
    float* out = (float*)d_out;
    const int N = in_sizes[0] / 3;

    hipLaunchKernelGGL(blob_sim_kernel, dim3(1), dim3(256), 0, stream,
                       initial_state, dyn_w1, dyn_b1, dyn_w2, dyn_b2,
                       coupling, damping, interaction, summ_w, summ_b,
                       fq_w1, fq_b1, fq_w2, fq_b2,
                       col_w1, col_b1, col_w2, col_b2, tP, ws);

    const int blocks = (N + 511) / 512;
    hipLaunchKernelGGL(field_kernel, dim3(blocks), dim3(256), 0, stream,
                       p, ws, out, N);
}